// Round 1
// baseline (388.154 us; speedup 1.0000x reference)
//
#include <hip/hip_runtime.h>
#include <stdint.h>
#include <math.h>

// ---------------------------------------------------------------------------
// JointAttention: dual-stream rmsnorm -> QKV proj -> RoPE -> joint attention
// over concat(a, x) (4096 tokens, 16 q-heads, 4 kv-heads tiled h%4) -> out proj.
// All matmuls in bf16 MFMA (16x16x32), fp32 accumulate. Threshold is 2% of
// max|ref| -> bf16 error budget is ~5x margin (see round notes).
// ---------------------------------------------------------------------------

#define NSEQ 2048
#define NJ   4096
#define DIMM 1024

typedef __attribute__((ext_vector_type(4))) float f32x4;
typedef __attribute__((ext_vector_type(8))) short bf16x8;
typedef __attribute__((ext_vector_type(4))) short bf16x4;

__device__ __forceinline__ unsigned short f2bf(float f) {
  union { float f; uint32_t u; } v; v.f = f;
  return (unsigned short)((v.u + 0x7FFFu + ((v.u >> 16) & 1u)) >> 16);
}

// ------------------------- RoPE tables (fp64 trig) -------------------------
__global__ __launch_bounds__(256) void rope_table_kernel(float* __restrict__ cosT,
                                                         float* __restrict__ sinT) {
  int idx = blockIdx.x * 256 + threadIdx.x;
  if (idx >= NSEQ * 32) return;
  int pos = idx >> 5, i = idx & 31;
  double inv = pow(10000.0, -(double)i / 32.0);
  double ang = (double)(2 * pos) * inv;   // t = pos * (4096/2048)
  cosT[idx] = (float)cos(ang);
  sinT[idx] = (float)sin(ang);
}

// --------------- weight cast+transpose: f32 [1024][N] -> bf16 [N][1024] ----
__global__ __launch_bounds__(256) void wcast_kernel(
    const float* __restrict__ wqa, const float* __restrict__ wqx,
    const float* __restrict__ wkva, const float* __restrict__ wkvx,
    const float* __restrict__ woa, const float* __restrict__ wox,
    unsigned short* __restrict__ WQT, unsigned short* __restrict__ WKVT,
    unsigned short* __restrict__ WOT) {
  __shared__ float tile[32][33];
  int z = blockIdx.z;
  int s = z & 1, ty = z >> 1;
  int N = (ty == 1) ? 512 : 1024;
  int n0 = blockIdx.y * 32;
  if (n0 >= N) return;
  int k0 = blockIdx.x * 32;
  const float* src = (z == 0) ? wqa : (z == 1) ? wqx : (z == 2) ? wkva
                   : (z == 3) ? wkvx : (z == 4) ? woa : wox;
  unsigned short* dst = (ty == 0) ? WQT + (size_t)s * 1024 * 1024
                      : (ty == 1) ? WKVT + (size_t)s * 512 * 1024
                                  : WOT + (size_t)s * 1024 * 1024;
  int t = threadIdx.x;
  int r = t >> 3, c4 = (t & 7) * 4;
  f32x4 v = *(const f32x4*)(src + (size_t)(k0 + r) * N + n0 + c4);
  tile[r][c4 + 0] = v.x; tile[r][c4 + 1] = v.y;
  tile[r][c4 + 2] = v.z; tile[r][c4 + 3] = v.w;
  __syncthreads();
  int nn = t >> 3, kk = (t & 7) * 4;
  bf16x4 o;
  o.x = (short)f2bf(tile[kk + 0][nn]);
  o.y = (short)f2bf(tile[kk + 1][nn]);
  o.z = (short)f2bf(tile[kk + 2][nn]);
  o.w = (short)f2bf(tile[kk + 3][nn]);
  *(bf16x4*)(dst + (size_t)(n0 + nn) * 1024 + k0 + kk) = o;
}

// ----------------------- rmsnorm + cast to bf16 ----------------------------
__global__ __launch_bounds__(256) void rmsnorm_kernel(
    const float* __restrict__ xa, const float* __restrict__ xx,
    const float* __restrict__ ga, const float* __restrict__ gx,
    unsigned short* __restrict__ XN) {
  int s = blockIdx.y, row = blockIdx.x;
  const float* src = (s == 0 ? xa : xx) + (size_t)row * DIMM;
  const float* g = (s == 0 ? ga : gx);
  int t = threadIdx.x;
  f32x4 v = *(const f32x4*)(src + t * 4);
  float ss = v.x * v.x + v.y * v.y + v.z * v.z + v.w * v.w;
#pragma unroll
  for (int o = 32; o > 0; o >>= 1) ss += __shfl_xor(ss, o, 64);
  __shared__ float red[4];
  if ((t & 63) == 0) red[t >> 6] = ss;
  __syncthreads();
  float tot = red[0] + red[1] + red[2] + red[3];
  float rs = rsqrtf(tot * (1.0f / DIMM) + 1e-6f);
  f32x4 gv = *(const f32x4*)(g + t * 4);
  bf16x4 o;
  o.x = (short)f2bf(v.x * rs * gv.x);
  o.y = (short)f2bf(v.y * rs * gv.y);
  o.z = (short)f2bf(v.z * rs * gv.z);
  o.w = (short)f2bf(v.w * rs * gv.w);
  *(bf16x4*)(XN + ((size_t)s * NSEQ + row) * DIMM + t * 4) = o;
}

// ---- shared 128x128x(K=1024) bf16 NT GEMM mainloop (BK=32, 4 waves) -------
__device__ __forceinline__ void gemm128_mainloop(
    const unsigned short* __restrict__ Ag, const unsigned short* __restrict__ Bg,
    unsigned short* As, unsigned short* Bs, f32x4 acc[4][4]) {
  int t = threadIdx.x;
  int lane = t & 63, wid = t >> 6;
  int wm = (wid >> 1) * 64, wn = (wid & 1) * 64;
  int l15 = lane & 15, quad = lane >> 4;
  int srow = t >> 2, sko = (t & 3) * 8;
#pragma unroll
  for (int mi = 0; mi < 4; ++mi)
#pragma unroll
    for (int j = 0; j < 4; ++j) acc[mi][j] = (f32x4){0.f, 0.f, 0.f, 0.f};
  for (int kt = 0; kt < 32; ++kt) {
    int k0 = kt * 32;
    bf16x8 a0 = *(const bf16x8*)(Ag + (size_t)srow * 1024 + k0 + sko);
    bf16x8 a1 = *(const bf16x8*)(Ag + (size_t)(srow + 64) * 1024 + k0 + sko);
    bf16x8 b0 = *(const bf16x8*)(Bg + (size_t)srow * 1024 + k0 + sko);
    bf16x8 b1 = *(const bf16x8*)(Bg + (size_t)(srow + 64) * 1024 + k0 + sko);
    __syncthreads();
    *(bf16x8*)(As + srow * 32 + sko) = a0;
    *(bf16x8*)(As + (srow + 64) * 32 + sko) = a1;
    *(bf16x8*)(Bs + srow * 32 + sko) = b0;
    *(bf16x8*)(Bs + (srow + 64) * 32 + sko) = b1;
    __syncthreads();
    bf16x8 af[4], bfr[4];
#pragma unroll
    for (int mi = 0; mi < 4; ++mi)
      af[mi] = *(const bf16x8*)(As + (wm + mi * 16 + l15) * 32 + quad * 8);
#pragma unroll
    for (int j = 0; j < 4; ++j)
      bfr[j] = *(const bf16x8*)(Bs + (wn + j * 16 + l15) * 32 + quad * 8);
#pragma unroll
    for (int mi = 0; mi < 4; ++mi)
#pragma unroll
      for (int j = 0; j < 4; ++j)
        acc[mi][j] = __builtin_amdgcn_mfma_f32_16x16x32_bf16(af[mi], bfr[j],
                                                             acc[mi][j], 0, 0, 0);
  }
}

// ------ QKV GEMM: A=[an;xn] (4096x1024), N=1536 (Q 1024 | K 256 | V 256) ---
// Epilogue: RoPE on q/k (q also * 1/64 = both softmax scales), per-head
// layouts QB[h][jr][d], KB[h][jr][d]; V -> VTMP[jr][hd] (transposed later).
__global__ __launch_bounds__(256) void gemm_qkv_kernel(
    const unsigned short* __restrict__ XN, const unsigned short* __restrict__ WQT,
    const unsigned short* __restrict__ WKVT, const float* __restrict__ cosT,
    const float* __restrict__ sinT, unsigned short* __restrict__ QB,
    unsigned short* __restrict__ KB, unsigned short* __restrict__ VTMP) {
  __shared__ unsigned short As[128 * 32], Bs[128 * 32];
  int n0 = blockIdx.x * 128, m0 = blockIdx.y * 128;
  int s = (m0 >= 2048) ? 1 : 0;
  const unsigned short* Ag = XN + (size_t)m0 * 1024;
  const unsigned short* Bg = (n0 < 1024)
      ? WQT + (size_t)s * 1024 * 1024 + (size_t)n0 * 1024
      : WKVT + (size_t)s * 512 * 1024 + (size_t)(n0 - 1024) * 1024;
  f32x4 acc[4][4];
  gemm128_mainloop(Ag, Bg, As, Bs, acc);
  int t = threadIdx.x, lane = t & 63, wid = t >> 6;
  int wm = (wid >> 1) * 64, wn = (wid & 1) * 64;
  int l15 = lane & 15, quad = lane >> 4;
  int coln = n0 + wn;                     // 64-aligned -> head-uniform per wave
  if (coln < 1280) {
    bool isq = coln < 1024;
    float sc = isq ? (1.0f / 64.0f) : 1.0f;
    unsigned short* dstBase;
    if (isq) dstBase = QB + (size_t)(coln >> 6) * NJ * 64;
    else     dstBase = KB + (size_t)((coln - 1024) >> 6) * NJ * 64;
#pragma unroll
    for (int mi = 0; mi < 4; ++mi)
#pragma unroll
      for (int r = 0; r < 4; ++r) {
        int jr = m0 + wm + mi * 16 + quad * 4 + r;   // joint row (a:0..2047, x:2048..)
        int pos = jr & 2047;
#pragma unroll
        for (int jp = 0; jp < 2; ++jp) {             // d = jp*16+l15 pairs with d+32
          int i = jp * 16 + l15;
          float c = cosT[pos * 32 + i], sn = sinT[pos * 32 + i];
          float x1 = acc[mi][jp][r], x2 = acc[mi][jp + 2][r];
          dstBase[(size_t)jr * 64 + jp * 16 + l15]      = f2bf((x1 * c - x2 * sn) * sc);
          dstBase[(size_t)jr * 64 + 32 + jp * 16 + l15] = f2bf((x2 * c + x1 * sn) * sc);
        }
      }
  } else {
    int cvb = coln - 1280;
#pragma unroll
    for (int mi = 0; mi < 4; ++mi)
#pragma unroll
      for (int j = 0; j < 4; ++j)
#pragma unroll
        for (int r = 0; r < 4; ++r) {
          int jr = m0 + wm + mi * 16 + quad * 4 + r;
          VTMP[(size_t)jr * 256 + cvb + j * 16 + l15] = f2bf(acc[mi][j][r]);
        }
  }
}

// --------- V transpose: VTMP [4096][256] -> VT [256(h*64+d)][4096] ---------
__global__ __launch_bounds__(256) void vtrans_kernel(
    const unsigned short* __restrict__ VTMP, unsigned short* __restrict__ VT) {
  __shared__ unsigned short tile[32][40];
  int r0 = blockIdx.x * 32, c0 = blockIdx.y * 32;
  int t = threadIdx.x;
  int r = t >> 3, c4 = (t & 7) * 4;
  bf16x4 v = *(const bf16x4*)(VTMP + (size_t)(r0 + r) * 256 + c0 + c4);
  tile[r][c4 + 0] = (unsigned short)v.x; tile[r][c4 + 1] = (unsigned short)v.y;
  tile[r][c4 + 2] = (unsigned short)v.z; tile[r][c4 + 3] = (unsigned short)v.w;
  __syncthreads();
  int nn = t >> 3, kk = (t & 7) * 4;
  bf16x4 o;
  o.x = (short)tile[kk + 0][nn]; o.y = (short)tile[kk + 1][nn];
  o.z = (short)tile[kk + 2][nn]; o.w = (short)tile[kk + 3][nn];
  *(bf16x4*)(VT + (size_t)(c0 + nn) * NJ + r0 + kk) = o;
}

// ------------------- flash attention: 64 q-rows x 1 head per block ---------
// K LDS [64key][64d +pad8], Vt LDS [64d][64key +pad8], P per-wave [16][64+8].
__global__ __launch_bounds__(256) void attn_kernel(
    const unsigned short* __restrict__ QB, const unsigned short* __restrict__ KB,
    const unsigned short* __restrict__ VT, unsigned short* __restrict__ AT) {
  __shared__ unsigned short Ks[64 * 72];
  __shared__ unsigned short Vs[64 * 72];
  __shared__ unsigned short Ps[4][16 * 72];
  int h = blockIdx.y, qt = blockIdx.x;
  int hk = h & 3;                               // jnp.tile -> kv head = h % 4
  int t = threadIdx.x, lane = t & 63, w = t >> 6;
  int l15 = lane & 15, quad = lane >> 4;
  int q0 = qt * 64 + w * 16;
  const unsigned short* qbase = QB + ((size_t)h * NJ + q0 + l15) * 64;
  bf16x8 qf0 = *(const bf16x8*)(qbase + quad * 8);
  bf16x8 qf1 = *(const bf16x8*)(qbase + 32 + quad * 8);
  f32x4 o[4];
#pragma unroll
  for (int j = 0; j < 4; ++j) o[j] = (f32x4){0.f, 0.f, 0.f, 0.f};
  float m_r[4] = {-INFINITY, -INFINITY, -INFINITY, -INFINITY};
  float l_r[4] = {0.f, 0.f, 0.f, 0.f};
  const unsigned short* Kg = KB + (size_t)hk * NJ * 64;
  const unsigned short* Vg = VT + (size_t)hk * 64 * NJ;
  int ky = t >> 3, dof = (t & 7) * 8;
  unsigned short* Pw = Ps[w];
  for (int kt = 0; kt < 64; ++kt) {
    int key0 = kt * 64;
    bf16x8 kr0 = *(const bf16x8*)(Kg + (size_t)(key0 + ky) * 64 + dof);
    bf16x8 kr1 = *(const bf16x8*)(Kg + (size_t)(key0 + 32 + ky) * 64 + dof);
    bf16x8 vr0 = *(const bf16x8*)(Vg + (size_t)ky * NJ + key0 + dof);
    bf16x8 vr1 = *(const bf16x8*)(Vg + (size_t)(32 + ky) * NJ + key0 + dof);
    __syncthreads();
    *(bf16x8*)(Ks + ky * 72 + dof) = kr0;
    *(bf16x8*)(Ks + (32 + ky) * 72 + dof) = kr1;
    *(bf16x8*)(Vs + ky * 72 + dof) = vr0;
    *(bf16x8*)(Vs + (32 + ky) * 72 + dof) = vr1;
    __syncthreads();
    // S = Q K^T  (C layout: row=quad*4+reg -> query, col=l15 -> key)
    f32x4 sx[4];
#pragma unroll
    for (int j = 0; j < 4; ++j) {
      const unsigned short* kp = Ks + (j * 16 + l15) * 72;
      bf16x8 kf0 = *(const bf16x8*)(kp + quad * 8);
      bf16x8 kf1 = *(const bf16x8*)(kp + 32 + quad * 8);
      f32x4 z = (f32x4){0.f, 0.f, 0.f, 0.f};
      z = __builtin_amdgcn_mfma_f32_16x16x32_bf16(qf0, kf0, z, 0, 0, 0);
      z = __builtin_amdgcn_mfma_f32_16x16x32_bf16(qf1, kf1, z, 0, 0, 0);
      sx[j] = z;
    }
    // online softmax per row (quad-local shuffle reductions over 16 key-lanes)
#pragma unroll
    for (int r = 0; r < 4; ++r) {
      float mx = fmaxf(fmaxf(sx[0][r], sx[1][r]), fmaxf(sx[2][r], sx[3][r]));
#pragma unroll
      for (int off = 1; off < 16; off <<= 1) mx = fmaxf(mx, __shfl_xor(mx, off, 64));
      float mnew = fmaxf(m_r[r], mx);
      float alpha = __expf(m_r[r] - mnew);
      float psum = 0.f;
#pragma unroll
      for (int j = 0; j < 4; ++j) {
        float p = __expf(sx[j][r] - mnew);
        sx[j][r] = p;
        psum += p;
      }
#pragma unroll
      for (int off = 1; off < 16; off <<= 1) psum += __shfl_xor(psum, off, 64);
      l_r[r] = l_r[r] * alpha + psum;
      m_r[r] = mnew;
      o[0][r] *= alpha; o[1][r] *= alpha; o[2][r] *= alpha; o[3][r] *= alpha;
    }
    // P: C layout -> A layout via wave-private LDS round trip
#pragma unroll
    for (int r = 0; r < 4; ++r)
#pragma unroll
      for (int j = 0; j < 4; ++j)
        Pw[(quad * 4 + r) * 72 + j * 16 + l15] = f2bf(sx[j][r]);
    bf16x8 pf0 = *(const bf16x8*)(Pw + l15 * 72 + quad * 8);
    bf16x8 pf1 = *(const bf16x8*)(Pw + l15 * 72 + 32 + quad * 8);
#pragma unroll
    for (int j = 0; j < 4; ++j) {
      const unsigned short* vp = Vs + (j * 16 + l15) * 72;
      bf16x8 vf0 = *(const bf16x8*)(vp + quad * 8);
      bf16x8 vf1 = *(const bf16x8*)(vp + 32 + quad * 8);
      o[j] = __builtin_amdgcn_mfma_f32_16x16x32_bf16(pf0, vf0, o[j], 0, 0, 0);
      o[j] = __builtin_amdgcn_mfma_f32_16x16x32_bf16(pf1, vf1, o[j], 0, 0, 0);
    }
  }
#pragma unroll
  for (int r = 0; r < 4; ++r) {
    float inv = 1.0f / l_r[r];
#pragma unroll
    for (int j = 0; j < 4; ++j)
      AT[(size_t)(q0 + quad * 4 + r) * DIMM + h * 64 + j * 16 + l15] =
          f2bf(o[j][r] * inv);
  }
}

// ---------------- output GEMM: AT (4096x1024) @ Wout^T + bias -> f32 -------
__global__ __launch_bounds__(256) void gemm_out_kernel(
    const unsigned short* __restrict__ AT, const unsigned short* __restrict__ WOT,
    const float* __restrict__ ba, const float* __restrict__ bx,
    float* __restrict__ out) {
  __shared__ unsigned short As[128 * 32], Bs[128 * 32];
  int n0 = blockIdx.x * 128, m0 = blockIdx.y * 128;
  int s = (m0 >= 2048) ? 1 : 0;                 // 0 = a-stream rows, 1 = x
  const unsigned short* Ag = AT + (size_t)m0 * 1024;
  const unsigned short* Bg = WOT + (size_t)s * 1024 * 1024 + (size_t)n0 * 1024;
  f32x4 acc[4][4];
  gemm128_mainloop(Ag, Bg, As, Bs, acc);
  int t = threadIdx.x, lane = t & 63, wid = t >> 6;
  int wm = (wid >> 1) * 64, wn = (wid & 1) * 64;
  int l15 = lane & 15, quad = lane >> 4;
  const float* bias = s ? bx : ba;
  // d_out = [out_x (2048x1024) | out_a (2048x1024)]
  float* obase = s ? (out + (size_t)(m0 - 2048) * 1024)
                   : (out + (size_t)2048 * 1024 + (size_t)m0 * 1024);
#pragma unroll
  for (int mi = 0; mi < 4; ++mi)
#pragma unroll
    for (int r = 0; r < 4; ++r) {
      int row = wm + mi * 16 + quad * 4 + r;
#pragma unroll
      for (int j = 0; j < 4; ++j) {
        int col = n0 + wn + j * 16 + l15;
        obase[(size_t)row * 1024 + col] = acc[mi][j][r] + bias[col];
      }
    }
}

// ---------------------------------------------------------------------------
extern "C" void kernel_launch(void* const* d_in, const int* in_sizes, int n_in,
                              void* d_out, int out_size, void* d_ws, size_t ws_size,
                              hipStream_t stream) {
  const float* x      = (const float*)d_in[0];
  const float* a      = (const float*)d_in[1];
  const float* g_x    = (const float*)d_in[2];
  const float* g_a    = (const float*)d_in[3];
  const float* Wq_x   = (const float*)d_in[4];
  const float* Wkv_x  = (const float*)d_in[5];
  const float* Wq_a   = (const float*)d_in[6];
  const float* Wkv_a  = (const float*)d_in[7];
  const float* Wout_x = (const float*)d_in[8];
  const float* bout_x = (const float*)d_in[9];
  const float* Wout_a = (const float*)d_in[10];
  const float* bout_a = (const float*)d_in[11];
  float* out = (float*)d_out;

  char* ws = (char*)d_ws;
  size_t off = 0;
  unsigned short* XN   = (unsigned short*)(ws + off); off += (size_t)NJ * 1024 * 2;      // 8 MB
  unsigned short* WQT  = (unsigned short*)(ws + off); off += (size_t)2 * 1024 * 1024 * 2; // 4 MB
  unsigned short* WKVT = (unsigned short*)(ws + off); off += (size_t)2 * 512 * 1024 * 2;  // 2 MB
  unsigned short* WOT  = (unsigned short*)(ws + off); off += (size_t)2 * 1024 * 1024 * 2; // 4 MB
  unsigned short* QB   = (unsigned short*)(ws + off); off += (size_t)16 * NJ * 64 * 2;    // 8 MB
  unsigned short* KB   = (unsigned short*)(ws + off); off += (size_t)4 * NJ * 64 * 2;     // 2 MB
  unsigned short* VT   = (unsigned short*)(ws + off); off += (size_t)4 * 64 * NJ * 2;     // 2 MB
  unsigned short* VTMP = (unsigned short*)(ws + off); off += (size_t)NJ * 256 * 2;        // 2 MB
  float* cosT = (float*)(ws + off); off += (size_t)NSEQ * 32 * 4;                         // 256 KB
  float* sinT = (float*)(ws + off); off += (size_t)NSEQ * 32 * 4;                         // 256 KB
  unsigned short* AT = XN;  // alias: XN is dead after gemm_qkv completes

  rope_table_kernel<<<dim3(256), dim3(256), 0, stream>>>(cosT, sinT);
  wcast_kernel<<<dim3(32, 32, 6), dim3(256), 0, stream>>>(
      Wq_a, Wq_x, Wkv_a, Wkv_x, Wout_a, Wout_x, WQT, WKVT, WOT);
  rmsnorm_kernel<<<dim3(2048, 2), dim3(256), 0, stream>>>(a, x, g_a, g_x, XN);
  gemm_qkv_kernel<<<dim3(12, 32), dim3(256), 0, stream>>>(
      XN, WQT, WKVT, cosT, sinT, QB, KB, VTMP);
  vtrans_kernel<<<dim3(128, 8), dim3(256), 0, stream>>>(VTMP, VT);
  attn_kernel<<<dim3(64, 16), dim3(256), 0, stream>>>(QB, KB, VT, AT);
  gemm_out_kernel<<<dim3(8, 32), dim3(256), 0, stream>>>(
      AT, WOT, bout_a, bout_x, out);
}